// Round 1
// baseline (9298.765 us; speedup 1.0000x reference)
//
#include <hip/hip_runtime.h>
#include <stdint.h>

#define B_ 128
#define T_ 512
#define D_ 1024
#define H_ 1024

typedef __attribute__((ext_vector_type(8))) short bf16x8;
typedef __attribute__((ext_vector_type(4))) float f32x4;

__device__ __forceinline__ ushort f2bf(float f) {
  union { float f; uint32_t u; } v; v.f = f;
  uint32_t u = v.u + 0x7FFFu + ((v.u >> 16) & 1u);
  return (ushort)(u >> 16);
}
__device__ __forceinline__ float bf2f(ushort s) {
  union { uint32_t u; float f; } v; v.u = ((uint32_t)s) << 16;
  return v.f;
}

__device__ __forceinline__ void store_xp(float* p, float v) { *p = v; }
__device__ __forceinline__ void store_xp(ushort* p, float v) { *p = f2bf(v); }
__device__ __forceinline__ float load_xp(const float* p) { return *p; }
__device__ __forceinline__ float load_xp(const ushort* p) { return bf2f(*p); }

// ---------------- W_hh -> (hi, lo) bf16 split ----------------
__global__ void wsplit_kernel(const float* __restrict__ W,
                              ushort* __restrict__ hi, ushort* __restrict__ lo,
                              int n) {
  int i = blockIdx.x * blockDim.x + threadIdx.x;
  if (i < n) {
    float w = W[i];
    ushort h = f2bf(w);
    hi[i] = h;
    lo[i] = f2bf(w - bf2f(h));
  }
}

// ---------------- zero h buffers ----------------
__global__ void hzero_kernel(uint4* __restrict__ p, int n4) {
  int i = blockIdx.x * blockDim.x + threadIdx.x;
  if (i < n4) p[i] = make_uint4(0, 0, 0, 0);
}

// ---------------- xp = x @ W_ih^T + b_ih + b_hh, stored [T,B,H] ----------------
// A = x [M=B*T, K=D] row-major fp32 (m = b*T + t), Bmat = W_ih [N=H, K=D] fp32.
// 128x128 tile, BK=32, 256 threads, 4 waves (2x2), each wave 64x64 (4x4 frags).
template <typename XPT>
__global__ __launch_bounds__(256) void xp_gemm(
    const float* __restrict__ x, const float* __restrict__ Wih,
    const float* __restrict__ bih, const float* __restrict__ bhh,
    XPT* __restrict__ xp) {
  __shared__ __align__(16) ushort As[128][40];
  __shared__ __align__(16) ushort Bs[128][40];
  const int tid = threadIdx.x;
  const int lane = tid & 63;
  const int w = tid >> 6;
  const int wm = w >> 1, wn = w & 1;
  const int bm = blockIdx.x;  // 512 M-tiles
  const int bn = blockIdx.y;  // 8 N-tiles

  f32x4 acc[4][4] = {};

  for (int kt = 0; kt < D_ / 32; ++kt) {
    __syncthreads();
#pragma unroll
    for (int i = 0; i < 4; ++i) {
      int c = tid + i * 256;      // 0..1023
      int isB = c >> 9;           // 0: A chunk, 1: B chunk
      int cc = c & 511;
      int row = cc >> 2;          // 0..127
      int col8 = (cc & 3) << 3;   // 0,8,16,24
      const float* src = isB
          ? (Wih + (size_t)(bn * 128 + row) * D_ + kt * 32 + col8)
          : (x + (size_t)(bm * 128 + row) * D_ + kt * 32 + col8);
      float4 f0 = *(const float4*)(src);
      float4 f1 = *(const float4*)(src + 4);
      uint32_t p0 = (uint32_t)f2bf(f0.x) | ((uint32_t)f2bf(f0.y) << 16);
      uint32_t p1 = (uint32_t)f2bf(f0.z) | ((uint32_t)f2bf(f0.w) << 16);
      uint32_t p2 = (uint32_t)f2bf(f1.x) | ((uint32_t)f2bf(f1.y) << 16);
      uint32_t p3 = (uint32_t)f2bf(f1.z) | ((uint32_t)f2bf(f1.w) << 16);
      uint4 pk = make_uint4(p0, p1, p2, p3);
      ushort* dst = isB ? &Bs[row][col8] : &As[row][col8];
      *(uint4*)dst = pk;
    }
    __syncthreads();

    bf16x8 af[4], bfr[4];
#pragma unroll
    for (int fm = 0; fm < 4; ++fm)
      af[fm] = *(const bf16x8*)&As[wm * 64 + fm * 16 + (lane & 15)][(lane >> 4) * 8];
#pragma unroll
    for (int fn = 0; fn < 4; ++fn)
      bfr[fn] = *(const bf16x8*)&Bs[wn * 64 + fn * 16 + (lane & 15)][(lane >> 4) * 8];
#pragma unroll
    for (int fm = 0; fm < 4; ++fm)
#pragma unroll
      for (int fn = 0; fn < 4; ++fn)
        acc[fm][fn] = __builtin_amdgcn_mfma_f32_16x16x32_bf16(
            af[fm], bfr[fn], acc[fm][fn], 0, 0, 0);
  }

  float bias[4];
#pragma unroll
  for (int fn = 0; fn < 4; ++fn) {
    int j = bn * 128 + wn * 64 + fn * 16 + (lane & 15);
    bias[fn] = bih[j] + bhh[j];
  }
#pragma unroll
  for (int fm = 0; fm < 4; ++fm) {
#pragma unroll
    for (int r = 0; r < 4; ++r) {
      int m = bm * 128 + wm * 64 + fm * 16 + ((lane >> 4) * 4) + r;
      int t = m & (T_ - 1);
      int b = m >> 9;  // m / T_
      size_t base = (size_t)t * (B_ * H_) + (size_t)b * H_;
#pragma unroll
      for (int fn = 0; fn < 4; ++fn) {
        int j = bn * 128 + wn * 64 + fn * 16 + (lane & 15);
        store_xp(xp + base + j, acc[fm][fn][r] + bias[fn]);
      }
    }
  }
}

// ---------------- one recurrence step ----------------
// h_new[b,j] = tanh(xp[t,b,j] + sum_k h[b,k]*W_hh[j,k]), split-bf16:
// acc = h_hi*W_hi + h_lo*W_hi + h_hi*W_lo  (fp32 MFMA accumulate)
// Tile: BM=32 (batch) x BN=32 (cols), grid (32,4)=128 blocks, 4 waves 2x2.
template <typename XPT>
__global__ __launch_bounds__(256) void rnn_step(
    const ushort* __restrict__ h_hi, const ushort* __restrict__ h_lo,
    const ushort* __restrict__ W_hi, const ushort* __restrict__ W_lo,
    const XPT* __restrict__ xp_t,
    ushort* __restrict__ ho_hi, ushort* __restrict__ ho_lo,
    float* __restrict__ out, int write_out) {
  __shared__ __align__(16) ushort Ah[32][40];
  __shared__ __align__(16) ushort Al[32][40];
  __shared__ __align__(16) ushort Bh[32][40];
  __shared__ __align__(16) ushort Bl[32][40];
  const int tid = threadIdx.x;
  const int lane = tid & 63;
  const int w = tid >> 6;
  const int wm = w >> 1, wn = w & 1;
  const int bn = blockIdx.x;  // 32 col tiles
  const int bm = blockIdx.y;  // 4 batch tiles

  f32x4 acc = {};

  for (int kt = 0; kt < H_ / 32; ++kt) {
    __syncthreads();
#pragma unroll
    for (int i = 0; i < 2; ++i) {
      int c = tid + i * 256;     // 0..511
      int sel = c >> 7;          // 0:Ah 1:Al 2:Bh 3:Bl (uniform per wave)
      int cc = c & 127;
      int row = cc >> 2;         // 0..31
      int col8 = (cc & 3) << 3;  // 0,8,16,24
      size_t goff_a = (size_t)(bm * 32 + row) * H_ + kt * 32 + col8;
      size_t goff_b = (size_t)(bn * 32 + row) * H_ + kt * 32 + col8;
      const ushort* src;
      ushort* dst;
      if (sel == 0)      { src = h_hi + goff_a; dst = &Ah[row][col8]; }
      else if (sel == 1) { src = h_lo + goff_a; dst = &Al[row][col8]; }
      else if (sel == 2) { src = W_hi + goff_b; dst = &Bh[row][col8]; }
      else               { src = W_lo + goff_b; dst = &Bl[row][col8]; }
      *(uint4*)dst = *(const uint4*)src;
    }
    __syncthreads();

    bf16x8 ah = *(const bf16x8*)&Ah[wm * 16 + (lane & 15)][(lane >> 4) * 8];
    bf16x8 al = *(const bf16x8*)&Al[wm * 16 + (lane & 15)][(lane >> 4) * 8];
    bf16x8 bh = *(const bf16x8*)&Bh[wn * 16 + (lane & 15)][(lane >> 4) * 8];
    bf16x8 bl = *(const bf16x8*)&Bl[wn * 16 + (lane & 15)][(lane >> 4) * 8];
    acc = __builtin_amdgcn_mfma_f32_16x16x32_bf16(ah, bh, acc, 0, 0, 0);
    acc = __builtin_amdgcn_mfma_f32_16x16x32_bf16(al, bh, acc, 0, 0, 0);
    acc = __builtin_amdgcn_mfma_f32_16x16x32_bf16(ah, bl, acc, 0, 0, 0);
  }

#pragma unroll
  for (int r = 0; r < 4; ++r) {
    int b = bm * 32 + wm * 16 + (lane >> 4) * 4 + r;
    int j = bn * 32 + wn * 16 + (lane & 15);
    float pre = acc[r] + load_xp(xp_t + (size_t)b * H_ + j);
    float hn = tanhf(pre);
    ushort hb = f2bf(hn);
    ho_hi[(size_t)b * H_ + j] = hb;
    ho_lo[(size_t)b * H_ + j] = f2bf(hn - bf2f(hb));
    if (write_out) out[(size_t)b * H_ + j] = hn;
  }
}

// ---------------- launch ----------------
extern "C" void kernel_launch(void* const* d_in, const int* in_sizes, int n_in,
                              void* d_out, int out_size, void* d_ws, size_t ws_size,
                              hipStream_t stream) {
  const float* x    = (const float*)d_in[0];
  const float* W_ih = (const float*)d_in[1];
  const float* W_hh = (const float*)d_in[2];
  const float* b_ih = (const float*)d_in[3];
  const float* b_hh = (const float*)d_in[4];
  float* out = (float*)d_out;

  const size_t xp_f32_bytes = (size_t)T_ * B_ * H_ * 4;   // 256 MB
  const size_t xp_bf_bytes  = xp_f32_bytes / 2;           // 128 MB
  const size_t wsp_bytes    = 2 * (size_t)H_ * H_ * 2;    // 4 MB (hi+lo)
  const size_t h_bytes      = 4 * (size_t)B_ * H_ * 2;    // 1 MB (hi/lo x 2 bufs)

  bool fp32xp = ws_size >= xp_f32_bytes + wsp_bytes + h_bytes;
  bool bf16xp = !fp32xp && ws_size >= xp_bf_bytes + wsp_bytes + h_bytes;
  if (!fp32xp && !bf16xp) return;  // insufficient workspace: fail loudly

  char* p = (char*)d_ws;
  size_t xp_bytes = fp32xp ? xp_f32_bytes : xp_bf_bytes;
  char* xp_raw = p;                       p += xp_bytes;
  ushort* Whi = (ushort*)p;               p += (size_t)H_ * H_ * 2;
  ushort* Wlo = (ushort*)p;               p += (size_t)H_ * H_ * 2;
  ushort* hbuf = (ushort*)p;              // 4 * B_*H_ ushorts
  ushort* hhi[2] = { hbuf, hbuf + (size_t)B_ * H_ };
  ushort* hlo[2] = { hbuf + 2 * (size_t)B_ * H_, hbuf + 3 * (size_t)B_ * H_ };

  // 1) split W_hh
  {
    int n = H_ * H_;
    wsplit_kernel<<<(n + 255) / 256, 256, 0, stream>>>(W_hh, Whi, Wlo, n);
  }
  // 2) zero h buffers (1 MB)
  {
    int n4 = (int)(h_bytes / 16);
    hzero_kernel<<<(n4 + 255) / 256, 256, 0, stream>>>((uint4*)hbuf, n4);
  }
  // 3) xp GEMM
  dim3 gxp(512, 8);
  if (fp32xp)
    xp_gemm<float><<<gxp, 256, 0, stream>>>(x, W_ih, b_ih, b_hh, (float*)xp_raw);
  else
    xp_gemm<ushort><<<gxp, 256, 0, stream>>>(x, W_ih, b_ih, b_hh, (ushort*)xp_raw);

  // 4) 512 recurrence steps, ping-pong h buffers
  dim3 gst(32, 4);
  for (int t = 0; t < T_; ++t) {
    int cur = t & 1, nxt = cur ^ 1;
    int wout = (t == T_ - 1) ? 1 : 0;
    if (fp32xp) {
      const float* xpt = (const float*)xp_raw + (size_t)t * B_ * H_;
      rnn_step<float><<<gst, 256, 0, stream>>>(hhi[cur], hlo[cur], Whi, Wlo,
                                               xpt, hhi[nxt], hlo[nxt], out, wout);
    } else {
      const ushort* xpt = (const ushort*)xp_raw + (size_t)t * B_ * H_;
      rnn_step<ushort><<<gst, 256, 0, stream>>>(hhi[cur], hlo[cur], Whi, Wlo,
                                                xpt, hhi[nxt], hlo[nxt], out, wout);
    }
  }
}